// Round 14
// baseline (231.499 us; speedup 1.0000x reference)
//
#include <hip/hip_runtime.h>
#include <hip/hip_bf16.h>
#include <stdint.h>

typedef __hip_bfloat16 bf16;
typedef __attribute__((ext_vector_type(8))) __bf16 bf16x8;
typedef __attribute__((ext_vector_type(4))) float f32x4;

__device__ __forceinline__ bf16x8 load8bf(const bf16* p) {
    return __builtin_bit_cast(bf16x8, *(const int4*)p);
}

__device__ __forceinline__ void async16(const bf16* g, bf16* l) {
    __builtin_amdgcn_global_load_lds((const __attribute__((address_space(1))) void*)g,
                                     (__attribute__((address_space(3))) void*)l, 16, 0, 0);
}

// ---------------- cast x (f32 -> bf16), vectorized ----------------
__global__ __launch_bounds__(256) void cast_x_kernel(const float* __restrict__ in,
                                                     bf16* __restrict__ out, int n4) {
    int i = blockIdx.x * 256 + threadIdx.x;
    if (i >= n4) return;
    float4 v = ((const float4*)in)[i];
    ushort4 o;
    o.x = __builtin_bit_cast(unsigned short, __float2bfloat16(v.x));
    o.y = __builtin_bit_cast(unsigned short, __float2bfloat16(v.y));
    o.z = __builtin_bit_cast(unsigned short, __float2bfloat16(v.z));
    o.w = __builtin_bit_cast(unsigned short, __float2bfloat16(v.w));
    ((ushort4*)out)[i] = o;
}

// ---------------- transpose + cast: in f32 [R][C] -> out bf16 [C][R] ----------------
__global__ __launch_bounds__(256) void transpose_cast(const float* __restrict__ in,
                                                      bf16* __restrict__ out, int R, int C) {
    __shared__ float t[32][33];
    int c0 = blockIdx.x * 32, r0 = blockIdx.y * 32;
    int tx = threadIdx.x, ty = threadIdx.y;
#pragma unroll
    for (int j = 0; j < 32; j += 8)
        t[ty + j][tx] = in[(size_t)(r0 + ty + j) * C + c0 + tx];
    __syncthreads();
#pragma unroll
    for (int j = 0; j < 32; j += 8)
        out[(size_t)(c0 + ty + j) * R + r0 + tx] = __float2bfloat16(t[tx][ty + j]);
}

// ---------------- GEMM: C[M][N] = A[M][K] * Bt[N][K]^T, bf16 in, MFMA 16x16x32 ----------------
// R14 = R13's 256x256 counted-vmcnt schedule with the staging BUG fixed.
// R13's NaN: global_load_lds dest is WAVE-UNIFORM base + lane*16 (m104, rule #21) — SHALFX's
// dest (tid>>2)*128+(tid&3)*16 bytes was not lane-linear, so half the tile was never written.
// STAGE_FULL's dest = s*8192 + tid*16 bytes = (wave-uniform s*8192 + w*1024) + lane*16: legal,
// same form as the verified R8/R12 staging. vmcnt arithmetic unchanged (4 loads per stage).
// Schedule per K-tile (2 barriers, loads in flight 1.5-2 tiles, never drain 0 mid-loop):
//   segA: stage (t+1).B -> other buf; 24 ds_reads from cur; 32 MFMA (m0-3)
//   MID:  lgkmcnt(0); s_barrier   (cur fully consumed -> segB's stage into cur.A is WAR-safe)
//   segB: stage (t+2).A -> cur buf; 32 MFMA (m4-7, register-resident)
//   END:  vmcnt(4); s_barrier     (retires (t+1).A,(t+1).B; leaves (t+2).A in flight)
// sched_barrier(0) pins every joint (R9 race -> R10 discipline). Swizzle: 0-conflict row&7
// both-sides XOR (R8-verified).
template <int MODE>
__global__ __launch_bounds__(512, 2) void gemm_bt(
    const bf16* __restrict__ A, const bf16* __restrict__ Bt,
    int M, int N, int K,
    bf16* __restrict__ qo, bf16* __restrict__ ko, bf16* __restrict__ vto,
    float* __restrict__ out, const float* __restrict__ bias) {
    __shared__ __align__(16) bf16 A0[256 * 64];   // 32 KB each
    __shared__ __align__(16) bf16 B0[256 * 64];
    __shared__ __align__(16) bf16 A1[256 * 64];
    __shared__ __align__(16) bf16 B1[256 * 64];
    const int tid = threadIdx.x;
    const int l = tid & 63, wid = tid >> 6;       // 8 waves
    const int lo = l & 15, hi = l >> 4;
    const int wm = wid & 1, wn = wid >> 1;        // 2m x 4n; wave tile 128x64
    const int m0 = blockIdx.x * 256, n0 = blockIdx.y * 256;

    f32x4 acc[8][4];
#pragma unroll
    for (int i = 0; i < 8; ++i)
#pragma unroll
        for (int j = 0; j < 4; ++j) acc[i][j] = f32x4{0.f, 0.f, 0.f, 0.f};

// stage a full 256x64 K-tile KT of SRC (rows BASE..BASE+255) into DST: 4 async16/thread.
// dest bytes = s*8192 + tid*16  (lane-linear within wave: REQUIRED by global_load_lds).
// source col chunk swizzled: c ^ (row&7)  (both-sides involution; read undoes it).
#define STAGE_FULL(SRC, BASE, DST, KT)                                                \
    _Pragma("unroll") for (int s_ = 0; s_ < 4; ++s_) {                                \
        int r_ = s_ * 64 + (tid >> 3);                                                \
        int c_ = tid & 7;                                                             \
        async16((SRC) + (size_t)((BASE) + r_) * K + (KT) * 64 + ((c_ ^ (r_ & 7)) * 8),\
                (DST) + s_ * 4096 + tid * 8);                                         \
    }

// One K-tile. AC/BC = current buffers (tile KT), BO = other B buffer ((KT+1).B dest).
// STG1: stage (KT+1).B; STG2: stage (KT+2).A into AC; ENDW: ENDW4 | ENDW0 | ENDWN.
#define TILE256(AC, BC, BO, KT, STG1, STG2, ENDW)                                     \
    {                                                                                 \
        if (STG1) { STAGE_FULL(Bt, n0, BO, (KT) + 1) }                                \
        __builtin_amdgcn_sched_barrier(0);                                            \
        bf16x8 a_[8][2], b_[4][2];                                                    \
        _Pragma("unroll") for (int mt = 0; mt < 8; ++mt) {                            \
            int ar = wm * 128 + mt * 16 + lo;                                         \
            _Pragma("unroll") for (int ks = 0; ks < 2; ++ks)                          \
                a_[mt][ks] = load8bf((AC) + ar * 64 +                                 \
                                     ((ks * 32 + hi * 8) ^ ((ar & 7) * 8)));          \
        }                                                                             \
        _Pragma("unroll") for (int nt = 0; nt < 4; ++nt) {                            \
            int br = wn * 64 + nt * 16 + lo;                                          \
            _Pragma("unroll") for (int ks = 0; ks < 2; ++ks)                          \
                b_[nt][ks] = load8bf((BC) + br * 64 +                                 \
                                     ((ks * 32 + hi * 8) ^ ((br & 7) * 8)));          \
        }                                                                             \
        __builtin_amdgcn_s_setprio(1);                                                \
        _Pragma("unroll") for (int mt = 0; mt < 4; ++mt)                              \
            _Pragma("unroll") for (int nt = 0; nt < 4; ++nt)                          \
                _Pragma("unroll") for (int ks = 0; ks < 2; ++ks)                      \
                    acc[mt][nt] = __builtin_amdgcn_mfma_f32_16x16x32_bf16(            \
                        a_[mt][ks], b_[nt][ks], acc[mt][nt], 0, 0, 0);                \
        __builtin_amdgcn_s_setprio(0);                                                \
        asm volatile("s_waitcnt lgkmcnt(0)" ::: "memory");                            \
        __builtin_amdgcn_sched_barrier(0);                                            \
        __builtin_amdgcn_s_barrier();        /* MID: cur fully consumed by all */     \
        __builtin_amdgcn_sched_barrier(0);                                            \
        if (STG2) { STAGE_FULL(A, m0, AC, (KT) + 2) }                                 \
        __builtin_amdgcn_sched_barrier(0);                                            \
        __builtin_amdgcn_s_setprio(1);                                                \
        _Pragma("unroll") for (int mt = 4; mt < 8; ++mt)                              \
            _Pragma("unroll") for (int nt = 0; nt < 4; ++nt)                          \
                _Pragma("unroll") for (int ks = 0; ks < 2; ++ks)                      \
                    acc[mt][nt] = __builtin_amdgcn_mfma_f32_16x16x32_bf16(            \
                        a_[mt][ks], b_[nt][ks], acc[mt][nt], 0, 0, 0);                \
        __builtin_amdgcn_s_setprio(0);                                                \
        __builtin_amdgcn_sched_barrier(0);                                            \
        ENDW                                                                          \
    }

#define ENDW4                                                                         \
    asm volatile("s_waitcnt vmcnt(4)" ::: "memory");                                  \
    __builtin_amdgcn_sched_barrier(0);                                                \
    __builtin_amdgcn_s_barrier();                                                     \
    __builtin_amdgcn_sched_barrier(0);
#define ENDW0                                                                         \
    asm volatile("s_waitcnt vmcnt(0)" ::: "memory");                                  \
    __builtin_amdgcn_sched_barrier(0);                                                \
    __builtin_amdgcn_s_barrier();                                                     \
    __builtin_amdgcn_sched_barrier(0);
#define ENDWN

    // prologue: tile0.A+B -> buf0, tile1.A -> buf1 (12 loads); vmcnt(4) retires tile0 (8),
    // leaves tile1.A in flight = steady-state entry condition.
    STAGE_FULL(A, m0, A0, 0)
    STAGE_FULL(Bt, n0, B0, 0)
    STAGE_FULL(A, m0, A1, 1)
    __builtin_amdgcn_sched_barrier(0);
    asm volatile("s_waitcnt vmcnt(4)" ::: "memory");
    __builtin_amdgcn_sched_barrier(0);
    __builtin_amdgcn_s_barrier();
    __builtin_amdgcn_sched_barrier(0);

    // K = 1024 -> 16 tiles. Main: tiles 0..13. Peeled: 14 (vmcnt(0)), 15 (no stage).
    for (int kt = 0; kt < 14; kt += 2) {
        TILE256(A0, B0, B1, kt, 1, 1, ENDW4)
        TILE256(A1, B1, B0, kt + 1, 1, 1, ENDW4)
    }
    TILE256(A0, B0, B1, 14, 1, 0, ENDW0)
    TILE256(A1, B1, B0, 15, 0, 0, ENDWN)
#undef ENDWN
#undef ENDW0
#undef ENDW4
#undef TILE256
#undef STAGE_FULL

#pragma unroll
    for (int mt = 0; mt < 8; ++mt)
#pragma unroll
        for (int nt = 0; nt < 4; ++nt)
#pragma unroll
            for (int r = 0; r < 4; ++r) {
                int row = m0 + wm * 128 + mt * 16 + hi * 4 + r;
                int col = n0 + wn * 64 + nt * 16 + lo;
                float v = acc[mt][nt][r];
                if (MODE == 0) {
                    if (col < 1024) {
                        qo[(size_t)row * 1024 + col] = __float2bfloat16(v * 0.125f);
                    } else if (col < 2048) {
                        ko[(size_t)row * 1024 + (col - 1024)] = __float2bfloat16(v);
                    } else {
                        int c = col - 2048;  // = h*64+d
                        vto[((size_t)(row >> 10) * 1024 + c) * 1024 + (row & 1023)] = __float2bfloat16(v);
                    }
                } else {
                    out[(size_t)row * N + col] = v + bias[col];
                }
            }
}

// ---------------- flash attention: grid = B*H*(N/128), 4 waves, 32 q-rows/wave ----------------
// (unchanged from R8: gload_lds double-buffer, XOR swizzle, no-max softmax, deferred l-sum)
__global__ __launch_bounds__(256, 3) void flash_attn(
    const bf16* __restrict__ q,    // [B*N][1024], q pre-scaled by 1/8
    const bf16* __restrict__ kin,  // [B*N][1024]
    const bf16* __restrict__ vt,   // [(b*1024 + h*64 + d)][1024] tokens
    bf16* __restrict__ out)        // [B*N][1024]
{
    __shared__ __align__(16) bf16 Kl0[64 * 64];
    __shared__ __align__(16) bf16 Vl0[64 * 64];
    __shared__ __align__(16) bf16 Kl1[64 * 64];
    __shared__ __align__(16) bf16 Vl1[64 * 64];
    __shared__ __align__(16) bf16 Pl[4 * 32 * 72];
    const int tid = threadIdx.x;
    const int l = tid & 63, w = tid >> 6;
    const int lo = l & 15, hi = l >> 4;
    const int bid = (blockIdx.x & 7) * 128 + (blockIdx.x >> 3);
    const int qt = bid & 7, h = (bid >> 3) & 15, b = bid >> 7;
    const int ts_r = tid >> 3;
    const int ts_c = tid & 7;
    const int ts_csw = (ts_c ^ (ts_r & 7)) * 8;
    const int ts_lds = tid * 8;

    const bf16* kbase = kin + (size_t)(b * 1024) * 1024 + h * 64;
    const bf16* vbase = vt + (size_t)(b * 1024 + h * 64) * 1024;

#define STAGE_KV(KD, VD, KT)                                                          \
    {                                                                                 \
        async16(kbase + (size_t)((KT) * 64 + ts_r) * 1024 + ts_csw, (KD) + ts_lds);   \
        async16(kbase + (size_t)((KT) * 64 + 32 + ts_r) * 1024 + ts_csw,              \
                (KD) + 2048 + ts_lds);                                                \
        async16(vbase + (size_t)ts_r * 1024 + (KT) * 64 + ts_csw, (VD) + ts_lds);     \
        async16(vbase + (size_t)(32 + ts_r) * 1024 + (KT) * 64 + ts_csw,              \
                (VD) + 2048 + ts_lds);                                                \
    }

    bf16x8 qf[2][2];
#pragma unroll
    for (int mt = 0; mt < 2; ++mt)
#pragma unroll
        for (int ks = 0; ks < 2; ++ks) {
            int tok = qt * 128 + w * 32 + mt * 16 + lo;
            qf[mt][ks] = load8bf(q + (size_t)(b * 1024 + tok) * 1024 + h * 64 + ks * 32 + hi * 8);
        }

    float lsum[2][4];
    f32x4 oacc[2][4];
#pragma unroll
    for (int mt = 0; mt < 2; ++mt)
#pragma unroll
        for (int r = 0; r < 4; ++r) lsum[mt][r] = 0.f;
#pragma unroll
    for (int mt = 0; mt < 2; ++mt)
#pragma unroll
        for (int nt = 0; nt < 4; ++nt) oacc[mt][nt] = f32x4{0.f, 0.f, 0.f, 0.f};

    STAGE_KV(Kl0, Vl0, 0)
    __syncthreads();

#define FA_ITER(KC, VC, KN, VN, KT, STG)                                              \
    {                                                                                 \
        if (STG) { STAGE_KV(KN, VN, (KT) + 1) }                                       \
        __builtin_amdgcn_sched_barrier(0);                                            \
        f32x4 s[2][4];                                                                \
        _Pragma("unroll") for (int mt = 0; mt < 2; ++mt)                              \
            _Pragma("unroll") for (int nt = 0; nt < 4; ++nt)                          \
                s[mt][nt] = f32x4{0.f, 0.f, 0.f, 0.f};                                \
        _Pragma("unroll") for (int ks = 0; ks < 2; ++ks) {                            \
            bf16x8 kf[4];                                                             \
            _Pragma("unroll") for (int nt = 0; nt < 4; ++nt) {                        \
                int kr = nt * 16 + lo;                                                \
                kf[nt] = load8bf((KC) + kr * 64 + ((ks * 32 + hi * 8) ^ ((kr & 7) * 8))); \
            }                                                                         \
            _Pragma("unroll") for (int mt = 0; mt < 2; ++mt)                          \
                _Pragma("unroll") for (int nt = 0; nt < 4; ++nt)                      \
                    s[mt][nt] = __builtin_amdgcn_mfma_f32_16x16x32_bf16(              \
                        qf[mt][ks], kf[nt], s[mt][nt], 0, 0, 0);                      \
        }                                                                             \
        _Pragma("unroll") for (int mt = 0; mt < 2; ++mt)                              \
            _Pragma("unroll") for (int nt = 0; nt < 4; ++nt)                          \
                _Pragma("unroll") for (int r = 0; r < 4; ++r) {                       \
                    float p = __expf(s[mt][nt][r]);                                   \
                    lsum[mt][r] += p;                                                 \
                    Pl[(w * 32 + mt * 16 + hi * 4 + r) * 72 + nt * 16 + lo] =         \
                        __float2bfloat16(p);                                          \
                }                                                                     \
        _Pragma("unroll") for (int ks = 0; ks < 2; ++ks) {                            \
            bf16x8 vf[4], pf[2];                                                      \
            _Pragma("unroll") for (int nt = 0; nt < 4; ++nt) {                        \
                int vr = nt * 16 + lo;                                                \
                vf[nt] = load8bf((VC) + vr * 64 + ((ks * 32 + hi * 8) ^ ((vr & 7) * 8))); \
            }                                                                         \
            _Pragma("unroll") for (int mt = 0; mt < 2; ++mt)                          \
                pf[mt] = load8bf(Pl + (w * 32 + mt * 16 + lo) * 72 + ks * 32 + hi * 8); \
            _Pragma("unroll") for (int mt = 0; mt < 2; ++mt)                          \
                _Pragma("unroll") for (int nt = 0; nt < 4; ++nt)                      \
                    oacc[mt][nt] = __builtin_amdgcn_mfma_f32_16x16x32_bf16(           \
                        pf[mt], vf[nt], oacc[mt][nt], 0, 0, 0);                       \
        }                                                                             \
        __syncthreads();                                                              \
    }

    for (int kt = 0; kt < 16; kt += 2) {
        FA_ITER(Kl0, Vl0, Kl1, Vl1, kt, true)
        FA_ITER(Kl1, Vl1, Kl0, Vl0, kt + 1, (kt + 2 < 16))
    }
#undef FA_ITER
#undef STAGE_KV

#pragma unroll
    for (int mt = 0; mt < 2; ++mt)
#pragma unroll
        for (int r = 0; r < 4; ++r) {
#pragma unroll
            for (int off = 1; off < 16; off <<= 1)
                lsum[mt][r] += __shfl_xor(lsum[mt][r], off);
        }

#pragma unroll
    for (int mt = 0; mt < 2; ++mt)
#pragma unroll
        for (int nt = 0; nt < 4; ++nt)
#pragma unroll
            for (int r = 0; r < 4; ++r) {
                int tok = qt * 128 + w * 32 + mt * 16 + hi * 4 + r;
                int d = nt * 16 + lo;
                out[(size_t)(b * 1024 + tok) * 1024 + h * 64 + d] =
                    __float2bfloat16(oacc[mt][nt][r] / lsum[mt][r]);
            }
}

extern "C" void kernel_launch(void* const* d_in, const int* in_sizes, int n_in,
                              void* d_out, int out_size, void* d_ws, size_t ws_size,
                              hipStream_t stream) {
    const float* x      = (const float*)d_in[0];
    const float* w_qkv  = (const float*)d_in[1];
    const float* w_proj = (const float*)d_in[2];
    const float* b_proj = (const float*)d_in[3];
    float* out = (float*)d_out;   // reference output dtype is float32

    char* ws = (char*)d_ws;
    bf16* xb     = (bf16*)(ws);                       // 16 MB [8192][1024]; reused as attn out
    bf16* wqkvT  = (bf16*)(ws + (16ull << 20));       //  6 MB [3072][1024]
    bf16* wprojT = (bf16*)(ws + (22ull << 20));       //  2 MB [1024][1024]
    bf16* qb     = (bf16*)(ws + (24ull << 20));       // 16 MB
    bf16* kb     = (bf16*)(ws + (40ull << 20));       // 16 MB
    bf16* vtb    = (bf16*)(ws + (56ull << 20));       // 16 MB  [b*1024 + h*64+d][1024]
    bf16* attn   = xb;                                // reuse (xb dead after QKV GEMM)

    cast_x_kernel<<<8192, 256, 0, stream>>>(x, xb, 2 * 1024 * 1024);
    transpose_cast<<<dim3(96, 32), dim3(32, 8), 0, stream>>>(w_qkv, wqkvT, 1024, 3072);
    transpose_cast<<<dim3(32, 32), dim3(32, 8), 0, stream>>>(w_proj, wprojT, 1024, 1024);
    gemm_bt<0><<<dim3(32, 12), 512, 0, stream>>>(xb, wqkvT, 8192, 3072, 1024,
                                                 qb, kb, vtb, nullptr, nullptr);
    flash_attn<<<1024, 256, 0, stream>>>(qb, kb, vtb, attn);
    gemm_bt<1><<<dim3(32, 4), 512, 0, stream>>>(attn, wprojT, 8192, 1024, 1024,
                                                nullptr, nullptr, nullptr, out, b_proj);
}

// Round 15
// 190.661 us; speedup vs baseline: 1.2142x; 1.2142x over previous
//
#include <hip/hip_runtime.h>
#include <hip/hip_bf16.h>
#include <stdint.h>

typedef __hip_bfloat16 bf16;
typedef __attribute__((ext_vector_type(8))) __bf16 bf16x8;
typedef __attribute__((ext_vector_type(4))) float f32x4;

__device__ __forceinline__ bf16x8 load8bf(const bf16* p) {
    return __builtin_bit_cast(bf16x8, *(const int4*)p);
}

__device__ __forceinline__ void async16(const bf16* g, bf16* l) {
    __builtin_amdgcn_global_load_lds((const __attribute__((address_space(1))) void*)g,
                                     (__attribute__((address_space(3))) void*)l, 16, 0, 0);
}

// ---------------- cast x (f32 -> bf16), vectorized ----------------
__global__ __launch_bounds__(256) void cast_x_kernel(const float* __restrict__ in,
                                                     bf16* __restrict__ out, int n4) {
    int i = blockIdx.x * 256 + threadIdx.x;
    if (i >= n4) return;
    float4 v = ((const float4*)in)[i];
    ushort4 o;
    o.x = __builtin_bit_cast(unsigned short, __float2bfloat16(v.x));
    o.y = __builtin_bit_cast(unsigned short, __float2bfloat16(v.y));
    o.z = __builtin_bit_cast(unsigned short, __float2bfloat16(v.z));
    o.w = __builtin_bit_cast(unsigned short, __float2bfloat16(v.w));
    ((ushort4*)out)[i] = o;
}

// ---------------- transpose + cast: in f32 [R][C] -> out bf16 [C][R] ----------------
__global__ __launch_bounds__(256) void transpose_cast(const float* __restrict__ in,
                                                      bf16* __restrict__ out, int R, int C) {
    __shared__ float t[32][33];
    int c0 = blockIdx.x * 32, r0 = blockIdx.y * 32;
    int tx = threadIdx.x, ty = threadIdx.y;
#pragma unroll
    for (int j = 0; j < 32; j += 8)
        t[ty + j][tx] = in[(size_t)(r0 + ty + j) * C + c0 + tx];
    __syncthreads();
#pragma unroll
    for (int j = 0; j < 32; j += 8)
        out[(size_t)(c0 + ty + j) * R + r0 + tx] = __float2bfloat16(t[tx][ty + j]);
}

// ---------------- GEMM: C[M][N] = A[M][K] * Bt[N][K]^T, bf16 in, MFMA 16x16x32 ----------------
// R15 = R14's (correctness-proven) 256x256 counted-vmcnt schedule with the SPILL fixed.
// R14 diagnosis: WRITE_SIZE 71MB vs 50 ideal (+21MB scratch = ~29 dwords/thread spilled);
// segA liveness acc(128)+a_[8][2](64)+b_(32)+addr(~40) = 264 > 256-reg budget (2 waves/SIMD).
// Fix: split the A-fragment reads. Reads of AC need only RETIRE before MID (lgkmcnt(0)) —
// they need not be simultaneously live. segA: read b_+a03 -> MFMA m0-3 -> read a47 (compiler
// reuses a03's dead registers under pressure) -> lgkmcnt(0) -> MID. Peak ~200 < 256.
// Schedule per K-tile (unchanged from R14):
//   segA: stage (t+1).B -> other buf; reads+MFMA m0-3; read a47
//   MID:  lgkmcnt(0); s_barrier   (cur fully consumed -> stage into cur.A is WAR-safe)
//   segB: stage (t+2).A -> cur buf; MFMA m4-7 (register-resident)
//   END:  vmcnt(4); s_barrier     (retires (t+1).A,B; leaves (t+2).A in flight)
// Staging dest is lane-linear (tid*16 bytes) per global_load_lds HW rule (R13 lesson).
// sched_barrier(0) pins all joints (R9/R10 discipline). Swizzle: 0-conflict row&7 both-sides.
template <int MODE>
__global__ __launch_bounds__(512, 2) void gemm_bt(
    const bf16* __restrict__ A, const bf16* __restrict__ Bt,
    int M, int N, int K,
    bf16* __restrict__ qo, bf16* __restrict__ ko, bf16* __restrict__ vto,
    float* __restrict__ out, const float* __restrict__ bias) {
    __shared__ __align__(16) bf16 A0[256 * 64];   // 32 KB each
    __shared__ __align__(16) bf16 B0[256 * 64];
    __shared__ __align__(16) bf16 A1[256 * 64];
    __shared__ __align__(16) bf16 B1[256 * 64];
    const int tid = threadIdx.x;
    const int l = tid & 63, wid = tid >> 6;       // 8 waves
    const int lo = l & 15, hi = l >> 4;
    const int wm = wid & 1, wn = wid >> 1;        // 2m x 4n; wave tile 128x64
    const int m0 = blockIdx.x * 256, n0 = blockIdx.y * 256;

    f32x4 acc[8][4];
#pragma unroll
    for (int i = 0; i < 8; ++i)
#pragma unroll
        for (int j = 0; j < 4; ++j) acc[i][j] = f32x4{0.f, 0.f, 0.f, 0.f};

// stage a full 256x64 K-tile KT of SRC (rows BASE..BASE+255) into DST: 4 async16/thread.
// dest bytes = s*8192 + tid*16 (lane-linear: REQUIRED by global_load_lds, rule #21/R13).
#define STAGE_FULL(SRC, BASE, DST, KT)                                                \
    _Pragma("unroll") for (int s_ = 0; s_ < 4; ++s_) {                                \
        int r_ = s_ * 64 + (tid >> 3);                                                \
        int c_ = tid & 7;                                                             \
        async16((SRC) + (size_t)((BASE) + r_) * K + (KT) * 64 + ((c_ ^ (r_ & 7)) * 8),\
                (DST) + s_ * 4096 + tid * 8);                                         \
    }

// One K-tile. AC/BC = current buffers (tile KT), BO = other B buffer ((KT+1).B dest).
// STG1: stage (KT+1).B; STG2: stage (KT+2).A into AC; ENDW: ENDW4 | ENDW0 | ENDWN.
#define TILE256(AC, BC, BO, KT, STG1, STG2, ENDW)                                     \
    {                                                                                 \
        if (STG1) { STAGE_FULL(Bt, n0, BO, (KT) + 1) }                                \
        __builtin_amdgcn_sched_barrier(0);                                            \
        bf16x8 b_[4][2], a03_[4][2];                                                  \
        _Pragma("unroll") for (int nt = 0; nt < 4; ++nt) {                            \
            int br = wn * 64 + nt * 16 + lo;                                          \
            _Pragma("unroll") for (int ks = 0; ks < 2; ++ks)                          \
                b_[nt][ks] = load8bf((BC) + br * 64 +                                 \
                                     ((ks * 32 + hi * 8) ^ ((br & 7) * 8)));          \
        }                                                                             \
        _Pragma("unroll") for (int mt = 0; mt < 4; ++mt) {                            \
            int ar = wm * 128 + mt * 16 + lo;                                         \
            _Pragma("unroll") for (int ks = 0; ks < 2; ++ks)                          \
                a03_[mt][ks] = load8bf((AC) + ar * 64 +                               \
                                       ((ks * 32 + hi * 8) ^ ((ar & 7) * 8)));        \
        }                                                                             \
        __builtin_amdgcn_s_setprio(1);                                                \
        _Pragma("unroll") for (int mt = 0; mt < 4; ++mt)                              \
            _Pragma("unroll") for (int nt = 0; nt < 4; ++nt)                          \
                _Pragma("unroll") for (int ks = 0; ks < 2; ++ks)                      \
                    acc[mt][nt] = __builtin_amdgcn_mfma_f32_16x16x32_bf16(            \
                        a03_[mt][ks], b_[nt][ks], acc[mt][nt], 0, 0, 0);              \
        __builtin_amdgcn_s_setprio(0);                                                \
        bf16x8 a47_[4][2];  /* reuses a03_'s dead registers under pressure */         \
        _Pragma("unroll") for (int mt = 0; mt < 4; ++mt) {                            \
            int ar = wm * 128 + (mt + 4) * 16 + lo;                                   \
            _Pragma("unroll") for (int ks = 0; ks < 2; ++ks)                          \
                a47_[mt][ks] = load8bf((AC) + ar * 64 +                               \
                                       ((ks * 32 + hi * 8) ^ ((ar & 7) * 8)));        \
        }                                                                             \
        asm volatile("s_waitcnt lgkmcnt(0)" ::: "memory");                            \
        __builtin_amdgcn_sched_barrier(0);                                            \
        __builtin_amdgcn_s_barrier();        /* MID: cur fully consumed by all */     \
        __builtin_amdgcn_sched_barrier(0);                                            \
        if (STG2) { STAGE_FULL(A, m0, AC, (KT) + 2) }                                 \
        __builtin_amdgcn_sched_barrier(0);                                            \
        __builtin_amdgcn_s_setprio(1);                                                \
        _Pragma("unroll") for (int mt = 0; mt < 4; ++mt)                              \
            _Pragma("unroll") for (int nt = 0; nt < 4; ++nt)                          \
                _Pragma("unroll") for (int ks = 0; ks < 2; ++ks)                      \
                    acc[mt + 4][nt] = __builtin_amdgcn_mfma_f32_16x16x32_bf16(        \
                        a47_[mt][ks], b_[nt][ks], acc[mt + 4][nt], 0, 0, 0);          \
        __builtin_amdgcn_s_setprio(0);                                                \
        __builtin_amdgcn_sched_barrier(0);                                            \
        ENDW                                                                          \
    }

#define ENDW4                                                                         \
    asm volatile("s_waitcnt vmcnt(4)" ::: "memory");                                  \
    __builtin_amdgcn_sched_barrier(0);                                                \
    __builtin_amdgcn_s_barrier();                                                     \
    __builtin_amdgcn_sched_barrier(0);
#define ENDW0                                                                         \
    asm volatile("s_waitcnt vmcnt(0)" ::: "memory");                                  \
    __builtin_amdgcn_sched_barrier(0);                                                \
    __builtin_amdgcn_s_barrier();                                                     \
    __builtin_amdgcn_sched_barrier(0);
#define ENDWN

    // prologue: tile0.A+B -> buf0, tile1.A -> buf1 (12 loads); vmcnt(4) retires tile0,
    // leaves tile1.A in flight = steady-state entry condition.
    STAGE_FULL(A, m0, A0, 0)
    STAGE_FULL(Bt, n0, B0, 0)
    STAGE_FULL(A, m0, A1, 1)
    __builtin_amdgcn_sched_barrier(0);
    asm volatile("s_waitcnt vmcnt(4)" ::: "memory");
    __builtin_amdgcn_sched_barrier(0);
    __builtin_amdgcn_s_barrier();
    __builtin_amdgcn_sched_barrier(0);

    // K = 1024 -> 16 tiles. Main: tiles 0..13. Peeled: 14 (vmcnt(0)), 15 (no stage).
    for (int kt = 0; kt < 14; kt += 2) {
        TILE256(A0, B0, B1, kt, 1, 1, ENDW4)
        TILE256(A1, B1, B0, kt + 1, 1, 1, ENDW4)
    }
    TILE256(A0, B0, B1, 14, 1, 0, ENDW0)
    TILE256(A1, B1, B0, 15, 0, 0, ENDWN)
#undef ENDWN
#undef ENDW0
#undef ENDW4
#undef TILE256
#undef STAGE_FULL

#pragma unroll
    for (int mt = 0; mt < 8; ++mt)
#pragma unroll
        for (int nt = 0; nt < 4; ++nt)
#pragma unroll
            for (int r = 0; r < 4; ++r) {
                int row = m0 + wm * 128 + mt * 16 + hi * 4 + r;
                int col = n0 + wn * 64 + nt * 16 + lo;
                float v = acc[mt][nt][r];
                if (MODE == 0) {
                    if (col < 1024) {
                        qo[(size_t)row * 1024 + col] = __float2bfloat16(v * 0.125f);
                    } else if (col < 2048) {
                        ko[(size_t)row * 1024 + (col - 1024)] = __float2bfloat16(v);
                    } else {
                        int c = col - 2048;  // = h*64+d
                        vto[((size_t)(row >> 10) * 1024 + c) * 1024 + (row & 1023)] = __float2bfloat16(v);
                    }
                } else {
                    out[(size_t)row * N + col] = v + bias[col];
                }
            }
}

// ---------------- flash attention: grid = B*H*(N/128), 4 waves, 32 q-rows/wave ----------------
// (unchanged from R8: gload_lds double-buffer, XOR swizzle, no-max softmax, deferred l-sum)
__global__ __launch_bounds__(256, 3) void flash_attn(
    const bf16* __restrict__ q,    // [B*N][1024], q pre-scaled by 1/8
    const bf16* __restrict__ kin,  // [B*N][1024]
    const bf16* __restrict__ vt,   // [(b*1024 + h*64 + d)][1024] tokens
    bf16* __restrict__ out)        // [B*N][1024]
{
    __shared__ __align__(16) bf16 Kl0[64 * 64];
    __shared__ __align__(16) bf16 Vl0[64 * 64];
    __shared__ __align__(16) bf16 Kl1[64 * 64];
    __shared__ __align__(16) bf16 Vl1[64 * 64];
    __shared__ __align__(16) bf16 Pl[4 * 32 * 72];
    const int tid = threadIdx.x;
    const int l = tid & 63, w = tid >> 6;
    const int lo = l & 15, hi = l >> 4;
    const int bid = (blockIdx.x & 7) * 128 + (blockIdx.x >> 3);
    const int qt = bid & 7, h = (bid >> 3) & 15, b = bid >> 7;
    const int ts_r = tid >> 3;
    const int ts_c = tid & 7;
    const int ts_csw = (ts_c ^ (ts_r & 7)) * 8;
    const int ts_lds = tid * 8;

    const bf16* kbase = kin + (size_t)(b * 1024) * 1024 + h * 64;
    const bf16* vbase = vt + (size_t)(b * 1024 + h * 64) * 1024;

#define STAGE_KV(KD, VD, KT)                                                          \
    {                                                                                 \
        async16(kbase + (size_t)((KT) * 64 + ts_r) * 1024 + ts_csw, (KD) + ts_lds);   \
        async16(kbase + (size_t)((KT) * 64 + 32 + ts_r) * 1024 + ts_csw,              \
                (KD) + 2048 + ts_lds);                                                \
        async16(vbase + (size_t)ts_r * 1024 + (KT) * 64 + ts_csw, (VD) + ts_lds);     \
        async16(vbase + (size_t)(32 + ts_r) * 1024 + (KT) * 64 + ts_csw,              \
                (VD) + 2048 + ts_lds);                                                \
    }

    bf16x8 qf[2][2];
#pragma unroll
    for (int mt = 0; mt < 2; ++mt)
#pragma unroll
        for (int ks = 0; ks < 2; ++ks) {
            int tok = qt * 128 + w * 32 + mt * 16 + lo;
            qf[mt][ks] = load8bf(q + (size_t)(b * 1024 + tok) * 1024 + h * 64 + ks * 32 + hi * 8);
        }

    float lsum[2][4];
    f32x4 oacc[2][4];
#pragma unroll
    for (int mt = 0; mt < 2; ++mt)
#pragma unroll
        for (int r = 0; r < 4; ++r) lsum[mt][r] = 0.f;
#pragma unroll
    for (int mt = 0; mt < 2; ++mt)
#pragma unroll
        for (int nt = 0; nt < 4; ++nt) oacc[mt][nt] = f32x4{0.f, 0.f, 0.f, 0.f};

    STAGE_KV(Kl0, Vl0, 0)
    __syncthreads();

#define FA_ITER(KC, VC, KN, VN, KT, STG)                                              \
    {                                                                                 \
        if (STG) { STAGE_KV(KN, VN, (KT) + 1) }                                       \
        __builtin_amdgcn_sched_barrier(0);                                            \
        f32x4 s[2][4];                                                                \
        _Pragma("unroll") for (int mt = 0; mt < 2; ++mt)                              \
            _Pragma("unroll") for (int nt = 0; nt < 4; ++nt)                          \
                s[mt][nt] = f32x4{0.f, 0.f, 0.f, 0.f};                                \
        _Pragma("unroll") for (int ks = 0; ks < 2; ++ks) {                            \
            bf16x8 kf[4];                                                             \
            _Pragma("unroll") for (int nt = 0; nt < 4; ++nt) {                        \
                int kr = nt * 16 + lo;                                                \
                kf[nt] = load8bf((KC) + kr * 64 + ((ks * 32 + hi * 8) ^ ((kr & 7) * 8))); \
            }                                                                         \
            _Pragma("unroll") for (int mt = 0; mt < 2; ++mt)                          \
                _Pragma("unroll") for (int nt = 0; nt < 4; ++nt)                      \
                    s[mt][nt] = __builtin_amdgcn_mfma_f32_16x16x32_bf16(              \
                        qf[mt][ks], kf[nt], s[mt][nt], 0, 0, 0);                      \
        }                                                                             \
        _Pragma("unroll") for (int mt = 0; mt < 2; ++mt)                              \
            _Pragma("unroll") for (int nt = 0; nt < 4; ++nt)                          \
                _Pragma("unroll") for (int r = 0; r < 4; ++r) {                       \
                    float p = __expf(s[mt][nt][r]);                                   \
                    lsum[mt][r] += p;                                                 \
                    Pl[(w * 32 + mt * 16 + hi * 4 + r) * 72 + nt * 16 + lo] =         \
                        __float2bfloat16(p);                                          \
                }                                                                     \
        _Pragma("unroll") for (int ks = 0; ks < 2; ++ks) {                            \
            bf16x8 vf[4], pf[2];                                                      \
            _Pragma("unroll") for (int nt = 0; nt < 4; ++nt) {                        \
                int vr = nt * 16 + lo;                                                \
                vf[nt] = load8bf((VC) + vr * 64 + ((ks * 32 + hi * 8) ^ ((vr & 7) * 8))); \
            }                                                                         \
            _Pragma("unroll") for (int mt = 0; mt < 2; ++mt)                          \
                pf[mt] = load8bf(Pl + (w * 32 + mt * 16 + lo) * 72 + ks * 32 + hi * 8); \
            _Pragma("unroll") for (int mt = 0; mt < 2; ++mt)                          \
                _Pragma("unroll") for (int nt = 0; nt < 4; ++nt)                      \
                    oacc[mt][nt] = __builtin_amdgcn_mfma_f32_16x16x32_bf16(           \
                        pf[mt], vf[nt], oacc[mt][nt], 0, 0, 0);                       \
        }                                                                             \
        __syncthreads();                                                              \
    }

    for (int kt = 0; kt < 16; kt += 2) {
        FA_ITER(Kl0, Vl0, Kl1, Vl1, kt, true)
        FA_ITER(Kl1, Vl1, Kl0, Vl0, kt + 1, (kt + 2 < 16))
    }
#undef FA_ITER
#undef STAGE_KV

#pragma unroll
    for (int mt = 0; mt < 2; ++mt)
#pragma unroll
        for (int r = 0; r < 4; ++r) {
#pragma unroll
            for (int off = 1; off < 16; off <<= 1)
                lsum[mt][r] += __shfl_xor(lsum[mt][r], off);
        }

#pragma unroll
    for (int mt = 0; mt < 2; ++mt)
#pragma unroll
        for (int nt = 0; nt < 4; ++nt)
#pragma unroll
            for (int r = 0; r < 4; ++r) {
                int tok = qt * 128 + w * 32 + mt * 16 + hi * 4 + r;
                int d = nt * 16 + lo;
                out[(size_t)(b * 1024 + tok) * 1024 + h * 64 + d] =
                    __float2bfloat16(oacc[mt][nt][r] / lsum[mt][r]);
            }
}

extern "C" void kernel_launch(void* const* d_in, const int* in_sizes, int n_in,
                              void* d_out, int out_size, void* d_ws, size_t ws_size,
                              hipStream_t stream) {
    const float* x      = (const float*)d_in[0];
    const float* w_qkv  = (const float*)d_in[1];
    const float* w_proj = (const float*)d_in[2];
    const float* b_proj = (const float*)d_in[3];
    float* out = (float*)d_out;   // reference output dtype is float32

    char* ws = (char*)d_ws;
    bf16* xb     = (bf16*)(ws);                       // 16 MB [8192][1024]; reused as attn out
    bf16* wqkvT  = (bf16*)(ws + (16ull << 20));       //  6 MB [3072][1024]
    bf16* wprojT = (bf16*)(ws + (22ull << 20));       //  2 MB [1024][1024]
    bf16* qb     = (bf16*)(ws + (24ull << 20));       // 16 MB
    bf16* kb     = (bf16*)(ws + (40ull << 20));       // 16 MB
    bf16* vtb    = (bf16*)(ws + (56ull << 20));       // 16 MB  [b*1024 + h*64+d][1024]
    bf16* attn   = xb;                                // reuse (xb dead after QKV GEMM)

    cast_x_kernel<<<8192, 256, 0, stream>>>(x, xb, 2 * 1024 * 1024);
    transpose_cast<<<dim3(96, 32), dim3(32, 8), 0, stream>>>(w_qkv, wqkvT, 1024, 3072);
    transpose_cast<<<dim3(32, 32), dim3(32, 8), 0, stream>>>(w_proj, wprojT, 1024, 1024);
    gemm_bt<0><<<dim3(32, 12), 512, 0, stream>>>(xb, wqkvT, 8192, 3072, 1024,
                                                 qb, kb, vtb, nullptr, nullptr);
    flash_attn<<<1024, 256, 0, stream>>>(qb, kb, vtb, attn);
    gemm_bt<1><<<dim3(32, 4), 512, 0, stream>>>(attn, wprojT, 8192, 1024, 1024,
                                                nullptr, nullptr, nullptr, out, b_proj);
}

// Round 16
// 153.595 us; speedup vs baseline: 1.5072x; 1.2413x over previous
//
#include <hip/hip_runtime.h>
#include <hip/hip_bf16.h>
#include <stdint.h>

typedef __hip_bfloat16 bf16;
typedef __attribute__((ext_vector_type(8))) __bf16 bf16x8;
typedef __attribute__((ext_vector_type(4))) float f32x4;

__device__ __forceinline__ bf16x8 load8bf(const bf16* p) {
    return __builtin_bit_cast(bf16x8, *(const int4*)p);
}

__device__ __forceinline__ void async16(const bf16* g, bf16* l) {
    __builtin_amdgcn_global_load_lds((const __attribute__((address_space(1))) void*)g,
                                     (__attribute__((address_space(3))) void*)l, 16, 0, 0);
}

// ---------------- cast x (f32 -> bf16), vectorized ----------------
__global__ __launch_bounds__(256) void cast_x_kernel(const float* __restrict__ in,
                                                     bf16* __restrict__ out, int n4) {
    int i = blockIdx.x * 256 + threadIdx.x;
    if (i >= n4) return;
    float4 v = ((const float4*)in)[i];
    ushort4 o;
    o.x = __builtin_bit_cast(unsigned short, __float2bfloat16(v.x));
    o.y = __builtin_bit_cast(unsigned short, __float2bfloat16(v.y));
    o.z = __builtin_bit_cast(unsigned short, __float2bfloat16(v.z));
    o.w = __builtin_bit_cast(unsigned short, __float2bfloat16(v.w));
    ((ushort4*)out)[i] = o;
}

// ---------------- transpose + cast: in f32 [R][C] -> out bf16 [C][R] ----------------
__global__ __launch_bounds__(256) void transpose_cast(const float* __restrict__ in,
                                                      bf16* __restrict__ out, int R, int C) {
    __shared__ float t[32][33];
    int c0 = blockIdx.x * 32, r0 = blockIdx.y * 32;
    int tx = threadIdx.x, ty = threadIdx.y;
#pragma unroll
    for (int j = 0; j < 32; j += 8)
        t[ty + j][tx] = in[(size_t)(r0 + ty + j) * C + c0 + tx];
    __syncthreads();
#pragma unroll
    for (int j = 0; j < 32; j += 8)
        out[(size_t)(c0 + ty + j) * R + r0 + tx] = __float2bfloat16(t[tx][ty + j]);
}

// ---------------- GEMM: C[M][N] = A[M][K] * Bt[N][K]^T, bf16 in, MFMA 16x16x32 ----------------
// MODE 0: QKV epilogue (split q/k/v, q*=0.125, v transposed).  MODE 1: +bias, f32 out.
// R16: m97-CANONICAL config — the one untested cell in the R8..R15 ledger.
// 128^2 tile, BK=64, SINGLE-buffered 32KB LDS (Al+Bl), stage -> sync -> 32 MFMA -> sync.
// launch_bounds(256,3): cap 170 regs (live ~156: acc 64 + frags 64 + addr; (256,4)'s 128 cap
// would spill — R3/R7 lesson). LDS 32KB + 3 waves/SIMD -> 3 blocks/CU = 12 waves (m97's
// operating point, 874 TF @4096^3). The drain-after-issue stall is absorbed by cross-block
// TLP (m114) instead of double-buffering (R8's dbuf cost half the occupancy: 2 blocks/CU).
// Ledger (rocprof QKV): R8 dbuf=97, R10=103, R12=105, R11=110, R15 256^2=135.
// Staging dest lane-linear (rule #21); both-sides row&7 XOR swizzle (0 conflicts, R8-verified).
template <int MODE>
__global__ __launch_bounds__(256, 3) void gemm_bt(
    const bf16* __restrict__ A, const bf16* __restrict__ Bt,
    int M, int N, int K,
    bf16* __restrict__ qo, bf16* __restrict__ ko, bf16* __restrict__ vto,
    float* __restrict__ out, const float* __restrict__ bias) {
    __shared__ __align__(16) bf16 Al[128 * 64];   // 16 KB
    __shared__ __align__(16) bf16 Bl[128 * 64];   // 16 KB
    const int tid = threadIdx.x;
    const int l = tid & 63, wid = tid >> 6;
    const int lo = l & 15, hi = l >> 4;
    const int wm = wid >> 1, wn = wid & 1;
    const int m0 = blockIdx.x * 128, n0 = blockIdx.y * 128;
    const int sr = tid >> 3;                    // staging row within 32 (4 sets of 32 rows)
    const int cl = (tid & 7) * 8;               // linear LDS chunk col (elems)
    const int csw = ((tid & 7) ^ (sr & 7)) * 8; // pre-swizzled global chunk col (elems)

    f32x4 acc[4][4];
#pragma unroll
    for (int i = 0; i < 4; ++i)
#pragma unroll
        for (int j = 0; j < 4; ++j) acc[i][j] = f32x4{0.f, 0.f, 0.f, 0.f};

    const int nkt = K / 64;
    for (int kt = 0; kt < nkt; ++kt) {
        // stage A-tile + B-tile (4+4 async16/thread); dest bytes = base + lane*16 (lane-linear)
#pragma unroll
        for (int s = 0; s < 4; ++s) {
            int r = s * 32 + sr;
            async16(A + (size_t)(m0 + r) * K + kt * 64 + csw, Al + r * 64 + cl);
        }
#pragma unroll
        for (int s = 0; s < 4; ++s) {
            int r = s * 32 + sr;
            async16(Bt + (size_t)(n0 + r) * K + kt * 64 + csw, Bl + r * 64 + cl);
        }
        __syncthreads();   // vmcnt(0) drain + visibility; stall absorbed by 3-block TLP
        {
            bf16x8 af[4][2], bfv[4][2];
#pragma unroll
            for (int mt = 0; mt < 4; ++mt) {
                int ar = wm * 64 + mt * 16 + lo;
#pragma unroll
                for (int ks = 0; ks < 2; ++ks)
                    af[mt][ks] = load8bf(Al + ar * 64 + ((ks * 32 + hi * 8) ^ ((ar & 7) * 8)));
            }
#pragma unroll
            for (int nt = 0; nt < 4; ++nt) {
                int br = wn * 64 + nt * 16 + lo;
#pragma unroll
                for (int ks = 0; ks < 2; ++ks)
                    bfv[nt][ks] = load8bf(Bl + br * 64 + ((ks * 32 + hi * 8) ^ ((br & 7) * 8)));
            }
#pragma unroll
            for (int mt = 0; mt < 4; ++mt)
#pragma unroll
                for (int nt = 0; nt < 4; ++nt)
#pragma unroll
                    for (int ks = 0; ks < 2; ++ks)
                        acc[mt][nt] = __builtin_amdgcn_mfma_f32_16x16x32_bf16(
                            af[mt][ks], bfv[nt][ks], acc[mt][nt], 0, 0, 0);
        }
        __syncthreads();   // WAR: all reads done before next iteration's stage overwrites
    }

#pragma unroll
    for (int mt = 0; mt < 4; ++mt)
#pragma unroll
        for (int nt = 0; nt < 4; ++nt)
#pragma unroll
            for (int r = 0; r < 4; ++r) {
                int row = m0 + wm * 64 + mt * 16 + hi * 4 + r;
                int col = n0 + wn * 64 + nt * 16 + lo;
                float v = acc[mt][nt][r];
                if (MODE == 0) {
                    if (col < 1024) {
                        qo[(size_t)row * 1024 + col] = __float2bfloat16(v * 0.125f);
                    } else if (col < 2048) {
                        ko[(size_t)row * 1024 + (col - 1024)] = __float2bfloat16(v);
                    } else {
                        int c = col - 2048;  // = h*64+d
                        vto[((size_t)(row >> 10) * 1024 + c) * 1024 + (row & 1023)] = __float2bfloat16(v);
                    }
                } else {
                    out[(size_t)row * N + col] = v + bias[col];
                }
            }
}

// ---------------- flash attention: grid = B*H*(N/128), 4 waves, 32 q-rows/wave ----------------
// (unchanged from R8: gload_lds double-buffer, XOR swizzle, no-max softmax, deferred l-sum)
__global__ __launch_bounds__(256, 3) void flash_attn(
    const bf16* __restrict__ q,    // [B*N][1024], q pre-scaled by 1/8
    const bf16* __restrict__ kin,  // [B*N][1024]
    const bf16* __restrict__ vt,   // [(b*1024 + h*64 + d)][1024] tokens
    bf16* __restrict__ out)        // [B*N][1024]
{
    __shared__ __align__(16) bf16 Kl0[64 * 64];
    __shared__ __align__(16) bf16 Vl0[64 * 64];
    __shared__ __align__(16) bf16 Kl1[64 * 64];
    __shared__ __align__(16) bf16 Vl1[64 * 64];
    __shared__ __align__(16) bf16 Pl[4 * 32 * 72];
    const int tid = threadIdx.x;
    const int l = tid & 63, w = tid >> 6;
    const int lo = l & 15, hi = l >> 4;
    const int bid = (blockIdx.x & 7) * 128 + (blockIdx.x >> 3);
    const int qt = bid & 7, h = (bid >> 3) & 15, b = bid >> 7;
    const int ts_r = tid >> 3;
    const int ts_c = tid & 7;
    const int ts_csw = (ts_c ^ (ts_r & 7)) * 8;
    const int ts_lds = tid * 8;

    const bf16* kbase = kin + (size_t)(b * 1024) * 1024 + h * 64;
    const bf16* vbase = vt + (size_t)(b * 1024 + h * 64) * 1024;

#define STAGE_KV(KD, VD, KT)                                                          \
    {                                                                                 \
        async16(kbase + (size_t)((KT) * 64 + ts_r) * 1024 + ts_csw, (KD) + ts_lds);   \
        async16(kbase + (size_t)((KT) * 64 + 32 + ts_r) * 1024 + ts_csw,              \
                (KD) + 2048 + ts_lds);                                                \
        async16(vbase + (size_t)ts_r * 1024 + (KT) * 64 + ts_csw, (VD) + ts_lds);     \
        async16(vbase + (size_t)(32 + ts_r) * 1024 + (KT) * 64 + ts_csw,              \
                (VD) + 2048 + ts_lds);                                                \
    }

    bf16x8 qf[2][2];
#pragma unroll
    for (int mt = 0; mt < 2; ++mt)
#pragma unroll
        for (int ks = 0; ks < 2; ++ks) {
            int tok = qt * 128 + w * 32 + mt * 16 + lo;
            qf[mt][ks] = load8bf(q + (size_t)(b * 1024 + tok) * 1024 + h * 64 + ks * 32 + hi * 8);
        }

    float lsum[2][4];
    f32x4 oacc[2][4];
#pragma unroll
    for (int mt = 0; mt < 2; ++mt)
#pragma unroll
        for (int r = 0; r < 4; ++r) lsum[mt][r] = 0.f;
#pragma unroll
    for (int mt = 0; mt < 2; ++mt)
#pragma unroll
        for (int nt = 0; nt < 4; ++nt) oacc[mt][nt] = f32x4{0.f, 0.f, 0.f, 0.f};

    STAGE_KV(Kl0, Vl0, 0)
    __syncthreads();

#define FA_ITER(KC, VC, KN, VN, KT, STG)                                              \
    {                                                                                 \
        if (STG) { STAGE_KV(KN, VN, (KT) + 1) }                                       \
        __builtin_amdgcn_sched_barrier(0);                                            \
        f32x4 s[2][4];                                                                \
        _Pragma("unroll") for (int mt = 0; mt < 2; ++mt)                              \
            _Pragma("unroll") for (int nt = 0; nt < 4; ++nt)                          \
                s[mt][nt] = f32x4{0.f, 0.f, 0.f, 0.f};                                \
        _Pragma("unroll") for (int ks = 0; ks < 2; ++ks) {                            \
            bf16x8 kf[4];                                                             \
            _Pragma("unroll") for (int nt = 0; nt < 4; ++nt) {                        \
                int kr = nt * 16 + lo;                                                \
                kf[nt] = load8bf((KC) + kr * 64 + ((ks * 32 + hi * 8) ^ ((kr & 7) * 8))); \
            }                                                                         \
            _Pragma("unroll") for (int mt = 0; mt < 2; ++mt)                          \
                _Pragma("unroll") for (int nt = 0; nt < 4; ++nt)                      \
                    s[mt][nt] = __builtin_amdgcn_mfma_f32_16x16x32_bf16(              \
                        qf[mt][ks], kf[nt], s[mt][nt], 0, 0, 0);                      \
        }                                                                             \
        _Pragma("unroll") for (int mt = 0; mt < 2; ++mt)                              \
            _Pragma("unroll") for (int nt = 0; nt < 4; ++nt)                          \
                _Pragma("unroll") for (int r = 0; r < 4; ++r) {                       \
                    float p = __expf(s[mt][nt][r]);                                   \
                    lsum[mt][r] += p;                                                 \
                    Pl[(w * 32 + mt * 16 + hi * 4 + r) * 72 + nt * 16 + lo] =         \
                        __float2bfloat16(p);                                          \
                }                                                                     \
        _Pragma("unroll") for (int ks = 0; ks < 2; ++ks) {                            \
            bf16x8 vf[4], pf[2];                                                      \
            _Pragma("unroll") for (int nt = 0; nt < 4; ++nt) {                        \
                int vr = nt * 16 + lo;                                                \
                vf[nt] = load8bf((VC) + vr * 64 + ((ks * 32 + hi * 8) ^ ((vr & 7) * 8))); \
            }                                                                         \
            _Pragma("unroll") for (int mt = 0; mt < 2; ++mt)                          \
                pf[mt] = load8bf(Pl + (w * 32 + mt * 16 + lo) * 72 + ks * 32 + hi * 8); \
            _Pragma("unroll") for (int mt = 0; mt < 2; ++mt)                          \
                _Pragma("unroll") for (int nt = 0; nt < 4; ++nt)                      \
                    oacc[mt][nt] = __builtin_amdgcn_mfma_f32_16x16x32_bf16(           \
                        pf[mt], vf[nt], oacc[mt][nt], 0, 0, 0);                       \
        }                                                                             \
        __syncthreads();                                                              \
    }

    for (int kt = 0; kt < 16; kt += 2) {
        FA_ITER(Kl0, Vl0, Kl1, Vl1, kt, true)
        FA_ITER(Kl1, Vl1, Kl0, Vl0, kt + 1, (kt + 2 < 16))
    }
#undef FA_ITER
#undef STAGE_KV

#pragma unroll
    for (int mt = 0; mt < 2; ++mt)
#pragma unroll
        for (int r = 0; r < 4; ++r) {
#pragma unroll
            for (int off = 1; off < 16; off <<= 1)
                lsum[mt][r] += __shfl_xor(lsum[mt][r], off);
        }

#pragma unroll
    for (int mt = 0; mt < 2; ++mt)
#pragma unroll
        for (int nt = 0; nt < 4; ++nt)
#pragma unroll
            for (int r = 0; r < 4; ++r) {
                int tok = qt * 128 + w * 32 + mt * 16 + hi * 4 + r;
                int d = nt * 16 + lo;
                out[(size_t)(b * 1024 + tok) * 1024 + h * 64 + d] =
                    __float2bfloat16(oacc[mt][nt][r] / lsum[mt][r]);
            }
}

extern "C" void kernel_launch(void* const* d_in, const int* in_sizes, int n_in,
                              void* d_out, int out_size, void* d_ws, size_t ws_size,
                              hipStream_t stream) {
    const float* x      = (const float*)d_in[0];
    const float* w_qkv  = (const float*)d_in[1];
    const float* w_proj = (const float*)d_in[2];
    const float* b_proj = (const float*)d_in[3];
    float* out = (float*)d_out;   // reference output dtype is float32

    char* ws = (char*)d_ws;
    bf16* xb     = (bf16*)(ws);                       // 16 MB [8192][1024]; reused as attn out
    bf16* wqkvT  = (bf16*)(ws + (16ull << 20));       //  6 MB [3072][1024]
    bf16* wprojT = (bf16*)(ws + (22ull << 20));       //  2 MB [1024][1024]
    bf16* qb     = (bf16*)(ws + (24ull << 20));       // 16 MB
    bf16* kb     = (bf16*)(ws + (40ull << 20));       // 16 MB
    bf16* vtb    = (bf16*)(ws + (56ull << 20));       // 16 MB  [b*1024 + h*64+d][1024]
    bf16* attn   = xb;                                // reuse (xb dead after QKV GEMM)

    cast_x_kernel<<<8192, 256, 0, stream>>>(x, xb, 2 * 1024 * 1024);
    transpose_cast<<<dim3(96, 32), dim3(32, 8), 0, stream>>>(w_qkv, wqkvT, 1024, 3072);
    transpose_cast<<<dim3(32, 32), dim3(32, 8), 0, stream>>>(w_proj, wprojT, 1024, 1024);
    gemm_bt<0><<<dim3(64, 24), 256, 0, stream>>>(xb, wqkvT, 8192, 3072, 1024,
                                                 qb, kb, vtb, nullptr, nullptr);
    flash_attn<<<1024, 256, 0, stream>>>(qb, kb, vtb, attn);
    gemm_bt<1><<<dim3(64, 8), 256, 0, stream>>>(attn, wprojT, 8192, 1024, 1024,
                                                nullptr, nullptr, nullptr, out, b_proj);
}